// Round 13
// baseline (556.795 us; speedup 1.0000x reference)
//
#include <hip/hip_runtime.h>
#include <hip/hip_bf16.h>

typedef __attribute__((ext_vector_type(8))) short bf16x8;
typedef __attribute__((ext_vector_type(4))) float f32x4;

__device__ __forceinline__ ushort bf16rne(float f) {
    uint u = __float_as_uint(f);
    return (ushort)((u + 0x7fffu + ((u >> 16) & 1u)) >> 16);
}
__device__ __forceinline__ void unpack2(uint p, float& a, float& b) {
    a = __uint_as_float(p << 16);
    b = __uint_as_float(p & 0xffff0000u);
}

// ---------------- bucketed graph preprocessing ----------------
// bucket = dst >> 8 (256 nodes per bucket), nbuck <= 512. Packed pair:
// (dst&255)<<24 | src  (src < 2^24).

__global__ __launch_bounds__(256) void k_bhist(const int* __restrict__ dst,
                                               int* __restrict__ bcnt, int E) {
    __shared__ int hist[512];
    int t = threadIdx.x;
    hist[t] = 0; hist[t + 256] = 0;
    __syncthreads();
    int off = blockIdx.x * 4096;
    int cnt = min(4096, E - off);
    for (int i = t; i < cnt; i += 256) atomicAdd(&hist[dst[off + i] >> 8], 1);
    __syncthreads();
    if (hist[t]) atomicAdd(&bcnt[t], hist[t]);
    if (hist[t + 256]) atomicAdd(&bcnt[t + 256], hist[t + 256]);
}

__global__ void k_bscan(const int* __restrict__ bcnt, int* __restrict__ bbase,
                        int* __restrict__ bcur, int nbuck) {
    __shared__ int s[512];
    int t = threadIdx.x;  // 512
    s[t] = (t < nbuck) ? bcnt[t] : 0;
    __syncthreads();
    for (int d = 1; d < 512; d <<= 1) {
        int u = (t >= d) ? s[t - d] : 0;
        __syncthreads();
        if (t >= d) s[t] += u;
        __syncthreads();
    }
    int excl = (t == 0) ? 0 : s[t - 1];
    bbase[t] = excl;
    if (t < nbuck) bcur[t] = excl;
    if (t == 511) bbase[512] = s[511];
}

__global__ __launch_bounds__(256) void k_binpack(const int* __restrict__ src,
                                                 const int* __restrict__ dst,
                                                 int* __restrict__ bcur,
                                                 uint* __restrict__ pairbuf,
                                                 int E, int nbuck) {
    __shared__ int hist[512];
    __shared__ int scn[512];
    __shared__ int cur[512];
    __shared__ int gbase[512];
    __shared__ uint sorted[4096];
    int t = threadIdx.x;
    int off = blockIdx.x * 4096;
    int cnt = min(4096, E - off);

    hist[t] = 0; hist[t + 256] = 0;
    __syncthreads();
    for (int i = t; i < cnt; i += 256) {
        int b = dst[off + i] >> 8;
        atomicAdd(&hist[b], 1);
    }
    __syncthreads();
    scn[t] = hist[t]; scn[t + 256] = hist[t + 256];
    __syncthreads();
    for (int d = 1; d < 256; d <<= 1) {
        int u0 = (t >= d) ? scn[t - d] : 0;
        int u1 = (t >= d) ? scn[256 + t - d] : 0;
        __syncthreads();
        if (t >= d) { scn[t] += u0; scn[256 + t] += u1; }
        __syncthreads();
    }
    int tot0 = scn[255];
    scn[256 + t] += tot0;
    __syncthreads();
    cur[t] = (t == 0) ? 0 : scn[t - 1];
    cur[t + 256] = scn[t + 255];
    if (t < nbuck && hist[t] > 0) gbase[t] = atomicAdd(&bcur[t], hist[t]);
    int t2 = t + 256;
    if (t2 < nbuck && hist[t2] > 0) gbase[t2] = atomicAdd(&bcur[t2], hist[t2]);
    __syncthreads();
    for (int i = t; i < cnt; i += 256) {
        int d = dst[off + i];
        int s = src[off + i];
        int b = d >> 8;
        int pos = atomicAdd(&cur[b], 1);
        sorted[pos] = ((uint)(d & 255) << 24) | (uint)s;
    }
    __syncthreads();
    int wid = t >> 6, lane = t & 63;
    for (int b = wid; b < nbuck; b += 4) {
        int n = hist[b];
        if (n == 0) continue;
        int ls = (b == 0) ? 0 : scn[b - 1];
        int gb = gbase[b];
        for (int j = lane; j < n; j += 64)
            pairbuf[gb + j] = sorted[ls + j];
    }
}

#define CSR_CAP 5632
__global__ __launch_bounds__(256) void k_csrbuild(const uint* __restrict__ pairbuf,
                                                  const int* __restrict__ bbase,
                                                  int* __restrict__ rowptr,
                                                  float* __restrict__ dinv,
                                                  int* __restrict__ csr,
                                                  int N, int nbuck) {
    __shared__ int lhist[256];
    __shared__ int scn[256];
    __shared__ int lcur[256];
    __shared__ int lcsr[CSR_CAP];
    int b = blockIdx.x;
    int base = b << 8;
    int nn = min(256, N - base);
    int lo = bbase[b], hi = bbase[b + 1];
    int cnt = hi - lo;
    int t = threadIdx.x;
    lhist[t] = 0;
    __syncthreads();
    for (int i = t; i < cnt; i += 256) atomicAdd(&lhist[pairbuf[lo + i] >> 24], 1);
    __syncthreads();
    int mydeg = lhist[t];
    scn[t] = mydeg;
    __syncthreads();
    for (int d = 1; d < 256; d <<= 1) {
        int u = (t >= d) ? scn[t - d] : 0;
        __syncthreads();
        if (t >= d) scn[t] += u;
        __syncthreads();
    }
    int excl = (t == 0) ? 0 : scn[t - 1];
    lcur[t] = excl;
    if (t < nn) {
        rowptr[base + t] = lo + excl;
        dinv[base + t] = rsqrtf((float)(mydeg + 1));  // +1 = self-loop
    }
    if (b == nbuck - 1 && t == 0) rowptr[N] = hi;
    __syncthreads();
    if (cnt <= CSR_CAP) {
        for (int i = t; i < cnt; i += 256) {
            uint p = pairbuf[lo + i];
            int pos = atomicAdd(&lcur[p >> 24], 1);
            lcsr[pos] = (int)(p & 0xFFFFFFu);
        }
        __syncthreads();
        for (int i = t; i < cnt; i += 256) csr[lo + i] = lcsr[i];
    } else {
        for (int i = t; i < cnt; i += 256) {
            uint p = pairbuf[lo + i];
            int pos = lo + atomicAdd(&lcur[p >> 24], 1);
            csr[pos] = (int)(p & 0xFFFFFFu);
        }
    }
}

// ---------------- weight transpose+cast (one kernel for W1, Wm, W2) ----------------
// w1t/wmt: [128][128] (n-major); w2t: [48][128] zero-padded (40 real cols).

__global__ void k_castT_all(const float* __restrict__ W1, const float* __restrict__ Wm,
                            const float* __restrict__ W2, ushort* __restrict__ w1t,
                            ushort* __restrict__ wmt, ushort* __restrict__ w2t) {
    int b = blockIdx.x;
    int t = threadIdx.x;
    if (b < 64) {
        int i = b * 256 + t; int k = i >> 7, n = i & 127;
        w1t[n * 128 + k] = bf16rne(W1[k * 128 + n]);
    } else if (b < 128) {
        int i = (b - 64) * 256 + t; int k = i >> 7, n = i & 127;
        wmt[n * 128 + k] = bf16rne(Wm[k * 128 + n]);
    } else {
        int i = (b - 128) * 256 + t;  // 0..6143 over [48][128]
        if (i < 6144) {
            int n = i >> 7, k = i & 127;
            w2t[n * 128 + k] = (n < 40) ? bf16rne(W2[k * 40 + n]) : (ushort)0;
        }
    }
}

// ==================== SLICED FEATURE LAYOUT ====================
// h[slice][node][16] bf16, slice = col >> 4 (8 slices of 16 cols).
// Each slice is 3.2 MB (N=100k) -> fits one XCD's 4 MB L2. Aggregation blocks
// take slice = blockIdx & 7, matching the XCD round-robin dispatch heuristic,
// so each XCD's gathers hit its own L2-resident slice instead of re-fetching
// the whole 25.6 MB array per XCD (the measured 188 MB compulsory traffic).

// ---------------- layer-1 GEMM: sliced C = (f32 x @ W1) * dinv[row] ----------------

__global__ __launch_bounds__(256) void k_gemm1(const float* __restrict__ A,
                                               const ushort* __restrict__ Wt,
                                               const float* __restrict__ dinv,
                                               ushort* __restrict__ C, int M) {
    int t = threadIdx.x;
    int wave = t >> 6, lane = t & 63;
    int m16 = lane & 15, quad = lane >> 4;
    int rowA = blockIdx.x * 64 + wave * 16 + m16;
    int rA = min(rowA, M - 1);
    const float4* A4 = (const float4*)A;  // 32 float4 per row

    f32x4 acc[8];
#pragma unroll
    for (int i = 0; i < 8; i++) acc[i] = (f32x4){0.f, 0.f, 0.f, 0.f};

#pragma unroll
    for (int it = 0; it < 4; it++) {
        float4 f0 = A4[(size_t)rA * 32 + 8 * it + 2 * quad];
        float4 f1 = A4[(size_t)rA * 32 + 8 * it + 2 * quad + 1];
        bf16x8 af;
        af[0] = (short)bf16rne(f0.x); af[1] = (short)bf16rne(f0.y);
        af[2] = (short)bf16rne(f0.z); af[3] = (short)bf16rne(f0.w);
        af[4] = (short)bf16rne(f1.x); af[5] = (short)bf16rne(f1.y);
        af[6] = (short)bf16rne(f1.z); af[7] = (short)bf16rne(f1.w);
#pragma unroll
        for (int nt = 0; nt < 8; nt++) {
            bf16x8 bfr = *(const bf16x8*)(Wt + (size_t)(nt * 16 + m16) * 128 + it * 32 + quad * 8);
            acc[nt] = __builtin_amdgcn_mfma_f32_16x16x32_bf16(af, bfr, acc[nt], 0, 0, 0);
        }
    }
    int rowBase = blockIdx.x * 64 + wave * 16 + quad * 4;
    float dnv[4];
#pragma unroll
    for (int r = 0; r < 4; r++) dnv[r] = dinv[min(rowBase + r, M - 1)];
#pragma unroll
    for (int nt = 0; nt < 8; nt++) {  // n-tile == slice
#pragma unroll
        for (int r = 0; r < 4; r++) {
            int row = rowBase + r;
            if (row < M) C[((size_t)nt * M + row) * 16 + m16] = bf16rne(acc[nt][r] * dnv[r]);
        }
    }
}

// ---------------- sliced aggregation: one slice per block, XCD-local ----------------
// 64 groups x 4 lanes; each group one node; per lane 8 B (uint2) of the 32 B
// slice row; edge loop x4 unroll -> 64 rows in flight per wave. csr via
// nontemporal loads (stream, don't evict the L2-resident slice). No LDS.

__global__ __launch_bounds__(256) void k_aggS(const ushort* __restrict__ g,
                                              const float* __restrict__ dinv,
                                              const int* __restrict__ rowptr,
                                              const int* __restrict__ csr,
                                              const float* __restrict__ bias,
                                              ushort* __restrict__ hout, int N) {
    int s = blockIdx.x & 7;        // slice -> XCD (dispatch round-robin heuristic)
    int chunk = blockIdx.x >> 3;
    int t = threadIdx.x;
    int grp = t >> 2;              // 0..63
    int l4 = t & 3;
    int node = chunk * 64 + grp;
    if (node >= N) return;
    const ushort* gs = g + (size_t)s * N * 16;
    float dn = dinv[node];
    float4 bb = *(const float4*)(bias + s * 16 + l4 * 4);
    float a0, a1, a2, a3;
    {
        uint2 p = *(const uint2*)(gs + (size_t)node * 16 + l4 * 4);
        unpack2(p.x, a0, a1);
        unpack2(p.y, a2, a3);
    }
    int e0 = rowptr[node], e1 = rowptr[node + 1];
    int e = e0;
    for (; e + 4 <= e1; e += 4) {
        int s0 = __builtin_nontemporal_load(csr + e);
        int s1 = __builtin_nontemporal_load(csr + e + 1);
        int s2 = __builtin_nontemporal_load(csr + e + 2);
        int s3 = __builtin_nontemporal_load(csr + e + 3);
        uint2 p0 = *(const uint2*)(gs + (size_t)s0 * 16 + l4 * 4);
        uint2 p1 = *(const uint2*)(gs + (size_t)s1 * 16 + l4 * 4);
        uint2 p2 = *(const uint2*)(gs + (size_t)s2 * 16 + l4 * 4);
        uint2 p3 = *(const uint2*)(gs + (size_t)s3 * 16 + l4 * 4);
        float u, v;
        unpack2(p0.x, u, v); a0 += u; a1 += v;
        unpack2(p0.y, u, v); a2 += u; a3 += v;
        unpack2(p1.x, u, v); a0 += u; a1 += v;
        unpack2(p1.y, u, v); a2 += u; a3 += v;
        unpack2(p2.x, u, v); a0 += u; a1 += v;
        unpack2(p2.y, u, v); a2 += u; a3 += v;
        unpack2(p3.x, u, v); a0 += u; a1 += v;
        unpack2(p3.y, u, v); a2 += u; a3 += v;
    }
    for (; e < e1; e++) {
        int s0 = __builtin_nontemporal_load(csr + e);
        uint2 p = *(const uint2*)(gs + (size_t)s0 * 16 + l4 * 4);
        float u, v;
        unpack2(p.x, u, v); a0 += u; a1 += v;
        unpack2(p.y, u, v); a2 += u; a3 += v;
    }
    float o0 = fmaxf(a0 * dn + bb.x, 0.f);
    float o1 = fmaxf(a1 * dn + bb.y, 0.f);
    float o2 = fmaxf(a2 * dn + bb.z, 0.f);
    float o3 = fmaxf(a3 * dn + bb.w, 0.f);
    uint2 q;
    q.x = (uint)bf16rne(o0) | ((uint)bf16rne(o1) << 16);
    q.y = (uint)bf16rne(o2) | ((uint)bf16rne(o3) << 16);
    *(uint2*)(hout + ((size_t)s * N + node) * 16 + l4 * 4) = q;
}

// ---------------- sliced GEMM: C_sliced = (A_sliced @ Wt) * dinv[row] ----------------
// NT n-tiles (8 -> 128 cols sliced out; 3 -> 40 cols plain out for layer 3).

template <int NT, bool SLICED_OUT>
__device__ __forceinline__ void gemm_sliced(const ushort* __restrict__ A,
                                            const ushort* __restrict__ Wt,
                                            const float* __restrict__ dinv,
                                            ushort* __restrict__ C, int M, int ccols) {
    int t = threadIdx.x;
    int wave = t >> 6, lane = t & 63;
    int m16 = lane & 15, quad = lane >> 4;
    int rowA = blockIdx.x * 64 + wave * 16 + m16;
    int rA = min(rowA, M - 1);

    f32x4 acc[NT];
#pragma unroll
    for (int i = 0; i < NT; i++) acc[i] = (f32x4){0.f, 0.f, 0.f, 0.f};

#pragma unroll
    for (int it = 0; it < 4; it++) {
        int k = it * 32 + quad * 8;
        int sl = k >> 4, ko = k & 15;
        bf16x8 af = *(const bf16x8*)(A + ((size_t)sl * M + rA) * 16 + ko);
#pragma unroll
        for (int nt = 0; nt < NT; nt++) {
            bf16x8 bfr = *(const bf16x8*)(Wt + (size_t)(nt * 16 + m16) * 128 + it * 32 + quad * 8);
            acc[nt] = __builtin_amdgcn_mfma_f32_16x16x32_bf16(af, bfr, acc[nt], 0, 0, 0);
        }
    }
    int rowBase = blockIdx.x * 64 + wave * 16 + quad * 4;
    float dnv[4];
#pragma unroll
    for (int r = 0; r < 4; r++) dnv[r] = dinv[min(rowBase + r, M - 1)];
#pragma unroll
    for (int nt = 0; nt < NT; nt++) {
        int col = nt * 16 + m16;
#pragma unroll
        for (int r = 0; r < 4; r++) {
            int row = rowBase + r;
            if (row >= M) continue;
            ushort val = bf16rne(acc[nt][r] * dnv[r]);
            if (SLICED_OUT) {
                C[((size_t)nt * M + row) * 16 + m16] = val;
            } else if (col < ccols) {
                C[(size_t)row * ccols + col] = val;
            }
        }
    }
}

__global__ __launch_bounds__(256) void k_gemmS(const ushort* __restrict__ A,
                                               const ushort* __restrict__ Wt,
                                               const float* __restrict__ dinv,
                                               ushort* __restrict__ C, int M) {
    gemm_sliced<8, true>(A, Wt, dinv, C, M, 128);
}

__global__ __launch_bounds__(256) void k_gemm3(const ushort* __restrict__ A,
                                               const ushort* __restrict__ Wt,
                                               const float* __restrict__ dinv,
                                               ushort* __restrict__ C, int M) {
    gemm_sliced<3, false>(A, Wt, dinv, C, M, 40);
}

// ---------------- final aggregation over 40-col rows (plain layout) ----------------
// 40-bf16 rows (80 B) = 10 lanes x uint2; 25 nodes per block; x4 unroll; fp32 out.

__global__ __launch_bounds__(256) void k_agg40_b(const ushort* __restrict__ g3,
                                                 const float* __restrict__ dinv,
                                                 const int* __restrict__ rowptr,
                                                 const int* __restrict__ csr,
                                                 const float* __restrict__ bias,
                                                 float* __restrict__ out, int N) {
    int t = threadIdx.x;
    if (t >= 250) return;
    int grp = t / 10;
    int l = t - grp * 10;
    int node = blockIdx.x * 25 + grp;
    if (node >= N) return;
    const uint2* gp = (const uint2*)g3;  // 10 uint2 per 40-bf16 row
    float dn = dinv[node];
    float a0, a1, a2, a3;
    {
        uint2 p = gp[(size_t)node * 10 + l];
        unpack2(p.x, a0, a1);
        unpack2(p.y, a2, a3);
    }
    int e0 = rowptr[node], e1 = rowptr[node + 1];
    int e = e0;
    for (; e + 4 <= e1; e += 4) {
        int s0 = csr[e], s1 = csr[e + 1], s2 = csr[e + 2], s3 = csr[e + 3];
        uint2 p0 = gp[(size_t)s0 * 10 + l];
        uint2 p1 = gp[(size_t)s1 * 10 + l];
        uint2 p2 = gp[(size_t)s2 * 10 + l];
        uint2 p3 = gp[(size_t)s3 * 10 + l];
        float u, v;
        unpack2(p0.x, u, v); a0 += u; a1 += v;
        unpack2(p0.y, u, v); a2 += u; a3 += v;
        unpack2(p1.x, u, v); a0 += u; a1 += v;
        unpack2(p1.y, u, v); a2 += u; a3 += v;
        unpack2(p2.x, u, v); a0 += u; a1 += v;
        unpack2(p2.y, u, v); a2 += u; a3 += v;
        unpack2(p3.x, u, v); a0 += u; a1 += v;
        unpack2(p3.y, u, v); a2 += u; a3 += v;
    }
    for (; e < e1; e++) {
        int s = csr[e];
        uint2 p = gp[(size_t)s * 10 + l];
        float u, v;
        unpack2(p.x, u, v); a0 += u; a1 += v;
        unpack2(p.y, u, v); a2 += u; a3 += v;
    }
    float4 bb = ((const float4*)bias)[l];
    float4 o;
    o.x = a0 * dn + bb.x;
    o.y = a1 * dn + bb.y;
    o.z = a2 * dn + bb.z;
    o.w = a3 * dn + bb.w;
    ((float4*)out)[(size_t)node * 10 + l] = o;
}

// ---------------- launch ----------------

extern "C" void kernel_launch(void* const* d_in, const int* in_sizes, int n_in,
                              void* d_out, int out_size, void* d_ws, size_t ws_size,
                              hipStream_t stream) {
    const float* x  = (const float*)d_in[0];
    const int* eidx = (const int*)d_in[1];
    const float* W1 = (const float*)d_in[2];
    const float* b1 = (const float*)d_in[3];
    const float* Wm = (const float*)d_in[4];
    const float* bm = (const float*)d_in[5];
    const float* W2 = (const float*)d_in[6];
    const float* b2 = (const float*)d_in[7];
    float* out = (float*)d_out;

    int N = in_sizes[0] / 128;
    int E = in_sizes[1] / 2;
    const int* src = eidx;
    const int* dst = eidx + E;
    int nbuck = (N + 255) >> 8;

    char* ws = (char*)d_ws;
    size_t off = 0;
    auto alloc = [&](size_t bytes) -> void* {
        void* p = ws + off;
        off += (bytes + 255) & ~(size_t)255;
        return p;
    };
    float*  dinv    = (float*)alloc((size_t)N * 4);
    int*    rowptr  = (int*)alloc(((size_t)N + 1) * 4);
    int*    csr     = (int*)alloc((size_t)E * 4);
    uint*   pairbuf = (uint*)alloc((size_t)E * 4);
    int*    bcnt    = (int*)alloc(512 * 4);
    int*    bbase   = (int*)alloc(513 * 4);
    int*    bcur    = (int*)alloc(512 * 4);
    ushort* w1t     = (ushort*)alloc(128 * 128 * 2);
    ushort* wmt     = (ushort*)alloc(128 * 128 * 2);
    ushort* w2t     = (ushort*)alloc(48 * 128 * 2);
    ushort* gbufS   = (ushort*)alloc((size_t)N * 128 * 2);  // sliced [8][N][16]
    ushort* hbufS   = (ushort*)alloc((size_t)N * 128 * 2);  // sliced [8][N][16]
    ushort* g3      = (ushort*)alloc((size_t)N * 40 * 2);   // plain [N][40]

    hipMemsetAsync(bcnt, 0, 512 * 4, stream);
    k_bhist<<<(E + 4095) / 4096, 256, 0, stream>>>(dst, bcnt, E);
    k_bscan<<<1, 512, 0, stream>>>(bcnt, bbase, bcur, nbuck);
    k_binpack<<<(E + 4095) / 4096, 256, 0, stream>>>(src, dst, bcur, pairbuf, E, nbuck);
    k_csrbuild<<<nbuck, 256, 0, stream>>>(pairbuf, bbase, rowptr, dinv, csr, N, nbuck);
    k_castT_all<<<152, 256, 0, stream>>>(W1, Wm, W2, w1t, wmt, w2t);

    int gblk64 = (N + 63) / 64;
    int aggGrid = ((N + 63) / 64) * 8;  // 8 slices, slice = blockIdx & 7
    // layer 1
    k_gemm1<<<gblk64, 256, 0, stream>>>(x, w1t, dinv, gbufS, N);
    k_aggS<<<aggGrid, 256, 0, stream>>>(gbufS, dinv, rowptr, csr, b1, hbufS, N);
    // layer 2
    k_gemmS<<<gblk64, 256, 0, stream>>>(hbufS, wmt, dinv, gbufS, N);
    k_aggS<<<aggGrid, 256, 0, stream>>>(gbufS, dinv, rowptr, csr, bm, hbufS, N);
    // layer 3
    k_gemm3<<<gblk64, 256, 0, stream>>>(hbufS, w2t, dinv, g3, N);
    k_agg40_b<<<(N + 24) / 25, 256, 0, stream>>>(g3, dinv, rowptr, csr, b2, out, N);
}

// Round 14
// 391.033 us; speedup vs baseline: 1.4239x; 1.4239x over previous
//
#include <hip/hip_runtime.h>
#include <hip/hip_bf16.h>

typedef __attribute__((ext_vector_type(8))) short bf16x8;
typedef __attribute__((ext_vector_type(4))) float f32x4;

__device__ __forceinline__ ushort bf16rne(float f) {
    uint u = __float_as_uint(f);
    return (ushort)((u + 0x7fffu + ((u >> 16) & 1u)) >> 16);
}
__device__ __forceinline__ void unpack2(uint p, float& a, float& b) {
    a = __uint_as_float(p << 16);
    b = __uint_as_float(p & 0xffff0000u);
}

// ---------------- merged castT + bucket histogram ----------------
// blocks 0..151: weight transpose+cast (w1t/wmt [128][128] n-major, w2t [48][128]
// zero-padded). blocks 152..: per-tile bucket histogram (bucket = dst>>8).

__global__ __launch_bounds__(256) void k_pre1(const float* __restrict__ W1,
                                              const float* __restrict__ Wm,
                                              const float* __restrict__ W2,
                                              ushort* __restrict__ w1t,
                                              ushort* __restrict__ wmt,
                                              ushort* __restrict__ w2t,
                                              const int* __restrict__ dst,
                                              int* __restrict__ bcnt, int E) {
    __shared__ int hist[512];
    int b = blockIdx.x;
    int t = threadIdx.x;
    if (b < 152) {
        if (b < 64) {
            int i = b * 256 + t; int k = i >> 7, n = i & 127;
            w1t[n * 128 + k] = bf16rne(W1[k * 128 + n]);
        } else if (b < 128) {
            int i = (b - 64) * 256 + t; int k = i >> 7, n = i & 127;
            wmt[n * 128 + k] = bf16rne(Wm[k * 128 + n]);
        } else {
            int i = (b - 128) * 256 + t;
            if (i < 6144) {
                int n = i >> 7, k = i & 127;
                w2t[n * 128 + k] = (n < 40) ? bf16rne(W2[k * 40 + n]) : (ushort)0;
            }
        }
        return;
    }
    // bhist body
    hist[t] = 0; hist[t + 256] = 0;
    __syncthreads();
    int off = (b - 152) * 4096;
    int cnt = min(4096, E - off);
    for (int i = t; i < cnt; i += 256) atomicAdd(&hist[dst[off + i] >> 8], 1);
    __syncthreads();
    if (hist[t]) atomicAdd(&bcnt[t], hist[t]);
    if (hist[t + 256]) atomicAdd(&bcnt[t + 256], hist[t + 256]);
}

__global__ void k_bscan(const int* __restrict__ bcnt, int* __restrict__ bbase,
                        int* __restrict__ bcur, int nbuck) {
    __shared__ int s[512];
    int t = threadIdx.x;  // 512
    s[t] = (t < nbuck) ? bcnt[t] : 0;
    __syncthreads();
    for (int d = 1; d < 512; d <<= 1) {
        int u = (t >= d) ? s[t - d] : 0;
        __syncthreads();
        if (t >= d) s[t] += u;
        __syncthreads();
    }
    int excl = (t == 0) ? 0 : s[t - 1];
    bbase[t] = excl;
    if (t < nbuck) bcur[t] = excl;
    if (t == 511) bbase[512] = s[511];
}

__global__ __launch_bounds__(256) void k_binpack(const int* __restrict__ src,
                                                 const int* __restrict__ dst,
                                                 int* __restrict__ bcur,
                                                 uint* __restrict__ pairbuf,
                                                 int E, int nbuck) {
    __shared__ int hist[512];
    __shared__ int scn[512];
    __shared__ int cur[512];
    __shared__ int gbase[512];
    __shared__ uint sorted[4096];
    int t = threadIdx.x;
    int off = blockIdx.x * 4096;
    int cnt = min(4096, E - off);

    hist[t] = 0; hist[t + 256] = 0;
    __syncthreads();
    for (int i = t; i < cnt; i += 256) {
        int b = dst[off + i] >> 8;
        atomicAdd(&hist[b], 1);
    }
    __syncthreads();
    scn[t] = hist[t]; scn[t + 256] = hist[t + 256];
    __syncthreads();
    for (int d = 1; d < 256; d <<= 1) {
        int u0 = (t >= d) ? scn[t - d] : 0;
        int u1 = (t >= d) ? scn[256 + t - d] : 0;
        __syncthreads();
        if (t >= d) { scn[t] += u0; scn[256 + t] += u1; }
        __syncthreads();
    }
    int tot0 = scn[255];
    scn[256 + t] += tot0;
    __syncthreads();
    cur[t] = (t == 0) ? 0 : scn[t - 1];
    cur[t + 256] = scn[t + 255];
    if (t < nbuck && hist[t] > 0) gbase[t] = atomicAdd(&bcur[t], hist[t]);
    int t2 = t + 256;
    if (t2 < nbuck && hist[t2] > 0) gbase[t2] = atomicAdd(&bcur[t2], hist[t2]);
    __syncthreads();
    for (int i = t; i < cnt; i += 256) {
        int d = dst[off + i];
        int s = src[off + i];
        int b = d >> 8;
        int pos = atomicAdd(&cur[b], 1);
        sorted[pos] = ((uint)(d & 255) << 24) | (uint)s;
    }
    __syncthreads();
    int wid = t >> 6, lane = t & 63;
    for (int b = wid; b < nbuck; b += 4) {
        int n = hist[b];
        if (n == 0) continue;
        int ls = (b == 0) ? 0 : scn[b - 1];
        int gb = gbase[b];
        for (int j = lane; j < n; j += 64)
            pairbuf[gb + j] = sorted[ls + j];
    }
}

// ---------------- merged csrbuild + layer-1 GEMM ----------------
// blocks 0..nbuck-1: CSR build (rowptr/dinv/csr from pairbuf).
// blocks nbuck..: gemm1 = x(f32) @ W1 -> UNSCALED bf16 g (no dinv dependency,
// which is what lets gemm1 co-schedule with csrbuild).

#define CSR_CAP 5632
__global__ __launch_bounds__(256) void k_mega(const uint* __restrict__ pairbuf,
                                              const int* __restrict__ bbase,
                                              int* __restrict__ rowptr,
                                              float* __restrict__ dinv,
                                              int* __restrict__ csr,
                                              int N, int nbuck,
                                              const float* __restrict__ A,
                                              const ushort* __restrict__ Wt,
                                              ushort* __restrict__ C, int M) {
    __shared__ int lhist[256];
    __shared__ int scn[256];
    __shared__ int lcur[256];
    __shared__ int lcsr[CSR_CAP];
    int t = threadIdx.x;
    if ((int)blockIdx.x >= nbuck) {
        // ---- gemm1 body ----
        int blk = blockIdx.x - nbuck;
        int wave = t >> 6, lane = t & 63;
        int m16 = lane & 15, quad = lane >> 4;
        int rowA = blk * 64 + wave * 16 + m16;
        int rA = min(rowA, M - 1);
        const float4* A4 = (const float4*)A;

        f32x4 acc[8];
#pragma unroll
        for (int i = 0; i < 8; i++) acc[i] = (f32x4){0.f, 0.f, 0.f, 0.f};
#pragma unroll
        for (int it = 0; it < 4; it++) {
            float4 f0 = A4[(size_t)rA * 32 + 8 * it + 2 * quad];
            float4 f1 = A4[(size_t)rA * 32 + 8 * it + 2 * quad + 1];
            bf16x8 af;
            af[0] = (short)bf16rne(f0.x); af[1] = (short)bf16rne(f0.y);
            af[2] = (short)bf16rne(f0.z); af[3] = (short)bf16rne(f0.w);
            af[4] = (short)bf16rne(f1.x); af[5] = (short)bf16rne(f1.y);
            af[6] = (short)bf16rne(f1.z); af[7] = (short)bf16rne(f1.w);
#pragma unroll
            for (int nt = 0; nt < 8; nt++) {
                bf16x8 bfr = *(const bf16x8*)(Wt + (size_t)(nt * 16 + m16) * 128 + it * 32 + quad * 8);
                acc[nt] = __builtin_amdgcn_mfma_f32_16x16x32_bf16(af, bfr, acc[nt], 0, 0, 0);
            }
        }
        int rowBase = blk * 64 + wave * 16 + quad * 4;
#pragma unroll
        for (int nt = 0; nt < 8; nt++) {
            int col = nt * 16 + m16;
#pragma unroll
            for (int r = 0; r < 4; r++) {
                int row = rowBase + r;
                if (row < M) C[(size_t)row * 128 + col] = bf16rne(acc[nt][r]);
            }
        }
        return;
    }
    // ---- csrbuild body ----
    int b = blockIdx.x;
    int base = b << 8;
    int nn = min(256, N - base);
    int lo = bbase[b], hi = bbase[b + 1];
    int cnt = hi - lo;
    lhist[t] = 0;
    __syncthreads();
    for (int i = t; i < cnt; i += 256) atomicAdd(&lhist[pairbuf[lo + i] >> 24], 1);
    __syncthreads();
    int mydeg = lhist[t];
    scn[t] = mydeg;
    __syncthreads();
    for (int d = 1; d < 256; d <<= 1) {
        int u = (t >= d) ? scn[t - d] : 0;
        __syncthreads();
        if (t >= d) scn[t] += u;
        __syncthreads();
    }
    int excl = (t == 0) ? 0 : scn[t - 1];
    lcur[t] = excl;
    if (t < nn) {
        rowptr[base + t] = lo + excl;
        dinv[base + t] = rsqrtf((float)(mydeg + 1));  // +1 = self-loop
    }
    if (b == nbuck - 1 && t == 0) rowptr[N] = hi;
    __syncthreads();
    if (cnt <= CSR_CAP) {
        for (int i = t; i < cnt; i += 256) {
            uint p = pairbuf[lo + i];
            int pos = atomicAdd(&lcur[p >> 24], 1);
            lcsr[pos] = (int)(p & 0xFFFFFFu);
        }
        __syncthreads();
        for (int i = t; i < cnt; i += 256) csr[lo + i] = lcsr[i];
    } else {
        for (int i = t; i < cnt; i += 256) {
            uint p = pairbuf[lo + i];
            int pos = lo + atomicAdd(&lcur[p >> 24], 1);
            csr[pos] = (int)(p & 0xFFFFFFu);
        }
    }
}

// ---------------- fused agg + GEMM (R12 structure, unscaled-g convention) ----------------
// Agg: 16 groups x 16 lanes claim nodes 0..31 via LDS counter (work stealing).
// Gather: 16 lanes x uint4 = one 256B row per load inst, x4 edge unroll, with
// per-edge dinv[s] (400 KB array, L2-hot, broadcast across the group; add
// becomes fmac). Epilogue h = relu(dn*acc + bias) -> padded LDS [32][136].
// GEMM: 4 waves = 2 row-halves x 2 n-tile-halves; UNSCALED output.

template <int NT>  // total n-tiles in Wt (8 -> 128 cols, 3 -> 48/40 cols)
__device__ __forceinline__ void fused_agg_gemm(const ushort* __restrict__ g,
                                               const float* __restrict__ dinv,
                                               const int* __restrict__ rowptr,
                                               const int* __restrict__ csr,
                                               const float* __restrict__ bias,
                                               const ushort* __restrict__ Wt,
                                               ushort* __restrict__ C,
                                               int M, int ccols) {
    __shared__ ushort hs[32][136];
    __shared__ int nextNode;
    int t = threadIdx.x;
    if (t == 0) nextNode = 0;
    int l = t & 15;
    const uint4* g16 = (const uint4*)g;  // 16 uint4 per 128-bf16 row
    float4 bb0 = ((const float4*)bias)[2 * l];
    float4 bb1 = ((const float4*)bias)[2 * l + 1];
    __syncthreads();

    for (;;) {
        int idx = 0;
        if (l == 0) idx = atomicAdd(&nextNode, 1);
        idx = __shfl(idx, (t & 63) & ~15, 64);
        if (idx >= 32) break;
        int node = blockIdx.x * 32 + idx;
        int nd = min(node, M - 1);
        float dn = dinv[nd];
        float a[8];
        {
            uint4 p = g16[(size_t)nd * 16 + l];
            float u, v;
            unpack2(p.x, u, v); a[0] = u * dn; a[1] = v * dn;
            unpack2(p.y, u, v); a[2] = u * dn; a[3] = v * dn;
            unpack2(p.z, u, v); a[4] = u * dn; a[5] = v * dn;
            unpack2(p.w, u, v); a[6] = u * dn; a[7] = v * dn;
        }
        int e0 = rowptr[nd], e1 = rowptr[nd + 1];
        int e = e0;
        for (; e + 4 <= e1; e += 4) {
            int s0 = csr[e], s1 = csr[e + 1], s2 = csr[e + 2], s3 = csr[e + 3];
            float w0 = dinv[s0], w1 = dinv[s1], w2 = dinv[s2], w3 = dinv[s3];
            uint4 p0 = g16[(size_t)s0 * 16 + l];
            uint4 p1 = g16[(size_t)s1 * 16 + l];
            uint4 p2 = g16[(size_t)s2 * 16 + l];
            uint4 p3 = g16[(size_t)s3 * 16 + l];
            float u, v;
            unpack2(p0.x, u, v); a[0] += u * w0; a[1] += v * w0;
            unpack2(p0.y, u, v); a[2] += u * w0; a[3] += v * w0;
            unpack2(p0.z, u, v); a[4] += u * w0; a[5] += v * w0;
            unpack2(p0.w, u, v); a[6] += u * w0; a[7] += v * w0;
            unpack2(p1.x, u, v); a[0] += u * w1; a[1] += v * w1;
            unpack2(p1.y, u, v); a[2] += u * w1; a[3] += v * w1;
            unpack2(p1.z, u, v); a[4] += u * w1; a[5] += v * w1;
            unpack2(p1.w, u, v); a[6] += u * w1; a[7] += v * w1;
            unpack2(p2.x, u, v); a[0] += u * w2; a[1] += v * w2;
            unpack2(p2.y, u, v); a[2] += u * w2; a[3] += v * w2;
            unpack2(p2.z, u, v); a[4] += u * w2; a[5] += v * w2;
            unpack2(p2.w, u, v); a[6] += u * w2; a[7] += v * w2;
            unpack2(p3.x, u, v); a[0] += u * w3; a[1] += v * w3;
            unpack2(p3.y, u, v); a[2] += u * w3; a[3] += v * w3;
            unpack2(p3.z, u, v); a[4] += u * w3; a[5] += v * w3;
            unpack2(p3.w, u, v); a[6] += u * w3; a[7] += v * w3;
        }
        for (; e < e1; e++) {
            int s = csr[e];
            float w = dinv[s];
            uint4 p = g16[(size_t)s * 16 + l];
            float u, v;
            unpack2(p.x, u, v); a[0] += u * w; a[1] += v * w;
            unpack2(p.y, u, v); a[2] += u * w; a[3] += v * w;
            unpack2(p.z, u, v); a[4] += u * w; a[5] += v * w;
            unpack2(p.w, u, v); a[6] += u * w; a[7] += v * w;
        }
        float o0 = fmaxf(a[0] * dn + bb0.x, 0.f);
        float o1 = fmaxf(a[1] * dn + bb0.y, 0.f);
        float o2 = fmaxf(a[2] * dn + bb0.z, 0.f);
        float o3 = fmaxf(a[3] * dn + bb0.w, 0.f);
        float o4 = fmaxf(a[4] * dn + bb1.x, 0.f);
        float o5 = fmaxf(a[5] * dn + bb1.y, 0.f);
        float o6 = fmaxf(a[6] * dn + bb1.z, 0.f);
        float o7 = fmaxf(a[7] * dn + bb1.w, 0.f);
        uint4 qv;
        qv.x = (uint)bf16rne(o0) | ((uint)bf16rne(o1) << 16);
        qv.y = (uint)bf16rne(o2) | ((uint)bf16rne(o3) << 16);
        qv.z = (uint)bf16rne(o4) | ((uint)bf16rne(o5) << 16);
        qv.w = (uint)bf16rne(o6) | ((uint)bf16rne(o7) << 16);
        *(uint4*)&hs[idx][l * 8] = qv;
    }
    __syncthreads();

    // GEMM from LDS: 4 waves = 2 row-halves x 2 n-tile-halves; unscaled out.
    int wave = t >> 6, lane = t & 63;
    int m16 = lane & 15, quad = lane >> 4;
    int rowHalf = wave & 1;
    int ntHalf = wave >> 1;
    constexpr int NTH = (NT + 1) / 2;
    int ntStart = ntHalf * NTH;
    int ntEnd = ntHalf ? NT : NTH;

    f32x4 acc[NTH];
#pragma unroll
    for (int i = 0; i < NTH; i++) acc[i] = (f32x4){0.f, 0.f, 0.f, 0.f};
#pragma unroll
    for (int it = 0; it < 4; it++) {
        bf16x8 af = *(const bf16x8*)&hs[rowHalf * 16 + m16][it * 32 + quad * 8];
        for (int nt = ntStart; nt < ntEnd; nt++) {
            bf16x8 bfr = *(const bf16x8*)(Wt + (size_t)(nt * 16 + m16) * 128 + it * 32 + quad * 8);
            acc[nt - ntStart] = __builtin_amdgcn_mfma_f32_16x16x32_bf16(af, bfr, acc[nt - ntStart], 0, 0, 0);
        }
    }
    int rowBase = blockIdx.x * 32 + rowHalf * 16 + quad * 4;
    for (int nt = ntStart; nt < ntEnd; nt++) {
        int col = nt * 16 + m16;
        if (col >= ccols) continue;
#pragma unroll
        for (int r = 0; r < 4; r++) {
            int row = rowBase + r;
            if (row < M) C[(size_t)row * ccols + col] = bf16rne(acc[nt - ntStart][r]);
        }
    }
}

__global__ __launch_bounds__(256) void k_fusedA(const ushort* __restrict__ g,
                                                const float* __restrict__ dinv,
                                                const int* __restrict__ rowptr,
                                                const int* __restrict__ csr,
                                                const float* __restrict__ bias,
                                                const ushort* __restrict__ Wt,
                                                ushort* __restrict__ C, int M) {
    fused_agg_gemm<8>(g, dinv, rowptr, csr, bias, Wt, C, M, 128);
}

__global__ __launch_bounds__(256) void k_fusedB(const ushort* __restrict__ g,
                                                const float* __restrict__ dinv,
                                                const int* __restrict__ rowptr,
                                                const int* __restrict__ csr,
                                                const float* __restrict__ bias,
                                                const ushort* __restrict__ Wt,
                                                ushort* __restrict__ C, int M) {
    fused_agg_gemm<3>(g, dinv, rowptr, csr, bias, Wt, C, M, 40);
}

// ---------------- final aggregation over 40-col rows (unscaled g3) ----------------
// 40-bf16 rows (80 B) = 10 lanes x uint2; 25 nodes per block; x4 unroll; fp32 out.

__global__ __launch_bounds__(256) void k_agg40_b(const ushort* __restrict__ g3,
                                                 const float* __restrict__ dinv,
                                                 const int* __restrict__ rowptr,
                                                 const int* __restrict__ csr,
                                                 const float* __restrict__ bias,
                                                 float* __restrict__ out, int N) {
    int t = threadIdx.x;
    if (t >= 250) return;
    int grp = t / 10;
    int l = t - grp * 10;
    int node = blockIdx.x * 25 + grp;
    if (node >= N) return;
    const uint2* gp = (const uint2*)g3;  // 10 uint2 per 40-bf16 row
    float dn = dinv[node];
    float a0, a1, a2, a3;
    {
        uint2 p = gp[(size_t)node * 10 + l];
        float u, v;
        unpack2(p.x, u, v); a0 = u * dn; a1 = v * dn;
        unpack2(p.y, u, v); a2 = u * dn; a3 = v * dn;
    }
    int e0 = rowptr[node], e1 = rowptr[node + 1];
    int e = e0;
    for (; e + 4 <= e1; e += 4) {
        int s0 = csr[e], s1 = csr[e + 1], s2 = csr[e + 2], s3 = csr[e + 3];
        float w0 = dinv[s0], w1 = dinv[s1], w2 = dinv[s2], w3 = dinv[s3];
        uint2 p0 = gp[(size_t)s0 * 10 + l];
        uint2 p1 = gp[(size_t)s1 * 10 + l];
        uint2 p2 = gp[(size_t)s2 * 10 + l];
        uint2 p3 = gp[(size_t)s3 * 10 + l];
        float u, v;
        unpack2(p0.x, u, v); a0 += u * w0; a1 += v * w0;
        unpack2(p0.y, u, v); a2 += u * w0; a3 += v * w0;
        unpack2(p1.x, u, v); a0 += u * w1; a1 += v * w1;
        unpack2(p1.y, u, v); a2 += u * w1; a3 += v * w1;
        unpack2(p2.x, u, v); a0 += u * w2; a1 += v * w2;
        unpack2(p2.y, u, v); a2 += u * w2; a3 += v * w2;
        unpack2(p3.x, u, v); a0 += u * w3; a1 += v * w3;
        unpack2(p3.y, u, v); a2 += u * w3; a3 += v * w3;
    }
    for (; e < e1; e++) {
        int s = csr[e];
        float w = dinv[s];
        uint2 p = gp[(size_t)s * 10 + l];
        float u, v;
        unpack2(p.x, u, v); a0 += u * w; a1 += v * w;
        unpack2(p.y, u, v); a2 += u * w; a3 += v * w;
    }
    float4 bb = ((const float4*)bias)[l];
    float4 o;
    o.x = a0 * dn + bb.x;
    o.y = a1 * dn + bb.y;
    o.z = a2 * dn + bb.z;
    o.w = a3 * dn + bb.w;
    ((float4*)out)[(size_t)node * 10 + l] = o;
}

// ---------------- launch ----------------

extern "C" void kernel_launch(void* const* d_in, const int* in_sizes, int n_in,
                              void* d_out, int out_size, void* d_ws, size_t ws_size,
                              hipStream_t stream) {
    const float* x  = (const float*)d_in[0];
    const int* eidx = (const int*)d_in[1];
    const float* W1 = (const float*)d_in[2];
    const float* b1 = (const float*)d_in[3];
    const float* Wm = (const float*)d_in[4];
    const float* bm = (const float*)d_in[5];
    const float* W2 = (const float*)d_in[6];
    const float* b2 = (const float*)d_in[7];
    float* out = (float*)d_out;

    int N = in_sizes[0] / 128;
    int E = in_sizes[1] / 2;
    const int* src = eidx;
    const int* dst = eidx + E;
    int nbuck = (N + 255) >> 8;
    int ntile = (E + 4095) / 4096;

    char* ws = (char*)d_ws;
    size_t off = 0;
    auto alloc = [&](size_t bytes) -> void* {
        void* p = ws + off;
        off += (bytes + 255) & ~(size_t)255;
        return p;
    };
    float*  dinv    = (float*)alloc((size_t)N * 4);
    int*    rowptr  = (int*)alloc(((size_t)N + 1) * 4);
    int*    csr     = (int*)alloc((size_t)E * 4);
    uint*   pairbuf = (uint*)alloc((size_t)E * 4);
    int*    bcnt    = (int*)alloc(512 * 4);
    int*    bbase   = (int*)alloc(513 * 4);
    int*    bcur    = (int*)alloc(512 * 4);
    ushort* w1t     = (ushort*)alloc(128 * 128 * 2);
    ushort* wmt     = (ushort*)alloc(128 * 128 * 2);
    ushort* w2t     = (ushort*)alloc(48 * 128 * 2);
    ushort* gbuf    = (ushort*)alloc((size_t)N * 128 * 2);
    ushort* gbuf2   = (ushort*)alloc((size_t)N * 128 * 2);
    ushort* g3      = (ushort*)alloc((size_t)N * 40 * 2);

    int gblk64 = (N + 63) / 64;
    int gblk32 = (N + 31) / 32;

    hipMemsetAsync(bcnt, 0, 512 * 4, stream);
    // castT (152 blocks) || bhist (ntile blocks)
    k_pre1<<<152 + ntile, 256, 0, stream>>>(W1, Wm, W2, w1t, wmt, w2t, dst, bcnt, E);
    k_bscan<<<1, 512, 0, stream>>>(bcnt, bbase, bcur, nbuck);
    k_binpack<<<ntile, 256, 0, stream>>>(src, dst, bcur, pairbuf, E, nbuck);
    // csrbuild (nbuck blocks) || gemm1 (gblk64 blocks, unscaled output)
    k_mega<<<nbuck + gblk64, 256, 0, stream>>>(pairbuf, bbase, rowptr, dinv, csr,
                                               N, nbuck, x, w1t, gbuf, N);
    // layer-1 agg + layer-2 GEMM fused
    k_fusedA<<<gblk32, 256, 0, stream>>>(gbuf, dinv, rowptr, csr, b1, wmt, gbuf2, N);
    // layer-2 agg + layer-3 GEMM fused
    k_fusedB<<<gblk32, 256, 0, stream>>>(gbuf2, dinv, rowptr, csr, bm, w2t, g3, N);
    // final aggregation
    k_agg40_b<<<(N + 24) / 25, 256, 0, stream>>>(g3, dinv, rowptr, csr, b2, out, N);
}

// Round 15
// 368.339 us; speedup vs baseline: 1.5116x; 1.0616x over previous
//
#include <hip/hip_runtime.h>
#include <hip/hip_bf16.h>

typedef __attribute__((ext_vector_type(8))) short bf16x8;
typedef __attribute__((ext_vector_type(4))) float f32x4;

__device__ __forceinline__ ushort bf16rne(float f) {
    uint u = __float_as_uint(f);
    return (ushort)((u + 0x7fffu + ((u >> 16) & 1u)) >> 16);
}
__device__ __forceinline__ void unpack2(uint p, float& a, float& b) {
    a = __uint_as_float(p << 16);
    b = __uint_as_float(p & 0xffff0000u);
}

// ---------------- merged castT + bucket histogram ----------------
// blocks 0..151: weight transpose+cast. blocks 152..: bucket histogram.

__global__ __launch_bounds__(256) void k_pre1(const float* __restrict__ W1,
                                              const float* __restrict__ Wm,
                                              const float* __restrict__ W2,
                                              ushort* __restrict__ w1t,
                                              ushort* __restrict__ wmt,
                                              ushort* __restrict__ w2t,
                                              const int* __restrict__ dst,
                                              int* __restrict__ bcnt, int E) {
    __shared__ int hist[512];
    int b = blockIdx.x;
    int t = threadIdx.x;
    if (b < 152) {
        if (b < 64) {
            int i = b * 256 + t; int k = i >> 7, n = i & 127;
            w1t[n * 128 + k] = bf16rne(W1[k * 128 + n]);
        } else if (b < 128) {
            int i = (b - 64) * 256 + t; int k = i >> 7, n = i & 127;
            wmt[n * 128 + k] = bf16rne(Wm[k * 128 + n]);
        } else {
            int i = (b - 128) * 256 + t;
            if (i < 6144) {
                int n = i >> 7, k = i & 127;
                w2t[n * 128 + k] = (n < 40) ? bf16rne(W2[k * 40 + n]) : (ushort)0;
            }
        }
        return;
    }
    hist[t] = 0; hist[t + 256] = 0;
    __syncthreads();
    int off = (b - 152) * 4096;
    int cnt = min(4096, E - off);
    for (int i = t; i < cnt; i += 256) atomicAdd(&hist[dst[off + i] >> 8], 1);
    __syncthreads();
    if (hist[t]) atomicAdd(&bcnt[t], hist[t]);
    if (hist[t + 256]) atomicAdd(&bcnt[t + 256], hist[t + 256]);
}

__global__ void k_bscan(const int* __restrict__ bcnt, int* __restrict__ bbase,
                        int* __restrict__ bcur, int nbuck) {
    __shared__ int s[512];
    int t = threadIdx.x;  // 512
    s[t] = (t < nbuck) ? bcnt[t] : 0;
    __syncthreads();
    for (int d = 1; d < 512; d <<= 1) {
        int u = (t >= d) ? s[t - d] : 0;
        __syncthreads();
        if (t >= d) s[t] += u;
        __syncthreads();
    }
    int excl = (t == 0) ? 0 : s[t - 1];
    bbase[t] = excl;
    if (t < nbuck) bcur[t] = excl;
    if (t == 511) bbase[512] = s[511];
}

// ---------------- merged binpack + layer-1 GEMM (unscaled output) ----------------
// blocks 0..ntile-1: bucket-sort pack of edge pairs.
// blocks ntile.. : gemm1 = x(f32) @ W1 -> UNSCALED bf16 gbuf (no dinv dep ->
// co-schedules with binpack; binpack is LDS/atomic-bound, gemm1 MFMA/HBM-bound).

__global__ __launch_bounds__(256) void k_pack_gemm(const int* __restrict__ src,
                                                   const int* __restrict__ dst,
                                                   int* __restrict__ bcur,
                                                   uint* __restrict__ pairbuf,
                                                   int E, int nbuck, int ntile,
                                                   const float* __restrict__ A,
                                                   const ushort* __restrict__ Wt,
                                                   ushort* __restrict__ C, int M) {
    __shared__ int hist[512];
    __shared__ int scn[512];
    __shared__ int cur[512];
    __shared__ int gbase[512];
    __shared__ uint sorted[4096];
    int t = threadIdx.x;
    if ((int)blockIdx.x >= ntile) {
        // ---- gemm1 body (unscaled out) ----
        int blk = blockIdx.x - ntile;
        int wave = t >> 6, lane = t & 63;
        int m16 = lane & 15, quad = lane >> 4;
        int rowA = blk * 64 + wave * 16 + m16;
        int rA = min(rowA, M - 1);
        const float4* A4 = (const float4*)A;

        f32x4 acc[8];
#pragma unroll
        for (int i = 0; i < 8; i++) acc[i] = (f32x4){0.f, 0.f, 0.f, 0.f};
#pragma unroll
        for (int it = 0; it < 4; it++) {
            float4 f0 = A4[(size_t)rA * 32 + 8 * it + 2 * quad];
            float4 f1 = A4[(size_t)rA * 32 + 8 * it + 2 * quad + 1];
            bf16x8 af;
            af[0] = (short)bf16rne(f0.x); af[1] = (short)bf16rne(f0.y);
            af[2] = (short)bf16rne(f0.z); af[3] = (short)bf16rne(f0.w);
            af[4] = (short)bf16rne(f1.x); af[5] = (short)bf16rne(f1.y);
            af[6] = (short)bf16rne(f1.z); af[7] = (short)bf16rne(f1.w);
#pragma unroll
            for (int nt = 0; nt < 8; nt++) {
                bf16x8 bfr = *(const bf16x8*)(Wt + (size_t)(nt * 16 + m16) * 128 + it * 32 + quad * 8);
                acc[nt] = __builtin_amdgcn_mfma_f32_16x16x32_bf16(af, bfr, acc[nt], 0, 0, 0);
            }
        }
        int rowBase = blk * 64 + wave * 16 + quad * 4;
#pragma unroll
        for (int nt = 0; nt < 8; nt++) {
            int col = nt * 16 + m16;
#pragma unroll
            for (int r = 0; r < 4; r++) {
                int row = rowBase + r;
                if (row < M) C[(size_t)row * 128 + col] = bf16rne(acc[nt][r]);
            }
        }
        return;
    }
    // ---- binpack body ----
    int off = blockIdx.x * 4096;
    int cnt = min(4096, E - off);
    hist[t] = 0; hist[t + 256] = 0;
    __syncthreads();
    for (int i = t; i < cnt; i += 256) {
        int b = dst[off + i] >> 8;
        atomicAdd(&hist[b], 1);
    }
    __syncthreads();
    scn[t] = hist[t]; scn[t + 256] = hist[t + 256];
    __syncthreads();
    for (int d = 1; d < 256; d <<= 1) {
        int u0 = (t >= d) ? scn[t - d] : 0;
        int u1 = (t >= d) ? scn[256 + t - d] : 0;
        __syncthreads();
        if (t >= d) { scn[t] += u0; scn[256 + t] += u1; }
        __syncthreads();
    }
    int tot0 = scn[255];
    scn[256 + t] += tot0;
    __syncthreads();
    cur[t] = (t == 0) ? 0 : scn[t - 1];
    cur[t + 256] = scn[t + 255];
    if (t < nbuck && hist[t] > 0) gbase[t] = atomicAdd(&bcur[t], hist[t]);
    int t2 = t + 256;
    if (t2 < nbuck && hist[t2] > 0) gbase[t2] = atomicAdd(&bcur[t2], hist[t2]);
    __syncthreads();
    for (int i = t; i < cnt; i += 256) {
        int d = dst[off + i];
        int s = src[off + i];
        int b = d >> 8;
        int pos = atomicAdd(&cur[b], 1);
        sorted[pos] = ((uint)(d & 255) << 24) | (uint)s;
    }
    __syncthreads();
    int wid = t >> 6, lane = t & 63;
    for (int b = wid; b < nbuck; b += 4) {
        int n = hist[b];
        if (n == 0) continue;
        int ls = (b == 0) ? 0 : scn[b - 1];
        int gb = gbase[b];
        for (int j = lane; j < n; j += 64)
            pairbuf[gb + j] = sorted[ls + j];
    }
}

#define CSR_CAP 5632
__global__ __launch_bounds__(256) void k_csrbuild(const uint* __restrict__ pairbuf,
                                                  const int* __restrict__ bbase,
                                                  int* __restrict__ rowptr,
                                                  float* __restrict__ dinv,
                                                  int* __restrict__ csr,
                                                  int N, int nbuck) {
    __shared__ int lhist[256];
    __shared__ int scn[256];
    __shared__ int lcur[256];
    __shared__ int lcsr[CSR_CAP];
    int b = blockIdx.x;
    int base = b << 8;
    int nn = min(256, N - base);
    int lo = bbase[b], hi = bbase[b + 1];
    int cnt = hi - lo;
    int t = threadIdx.x;
    lhist[t] = 0;
    __syncthreads();
    for (int i = t; i < cnt; i += 256) atomicAdd(&lhist[pairbuf[lo + i] >> 24], 1);
    __syncthreads();
    int mydeg = lhist[t];
    scn[t] = mydeg;
    __syncthreads();
    for (int d = 1; d < 256; d <<= 1) {
        int u = (t >= d) ? scn[t - d] : 0;
        __syncthreads();
        if (t >= d) scn[t] += u;
        __syncthreads();
    }
    int excl = (t == 0) ? 0 : scn[t - 1];
    lcur[t] = excl;
    if (t < nn) {
        rowptr[base + t] = lo + excl;
        dinv[base + t] = rsqrtf((float)(mydeg + 1));  // +1 = self-loop
    }
    if (b == nbuck - 1 && t == 0) rowptr[N] = hi;
    __syncthreads();
    if (cnt <= CSR_CAP) {
        for (int i = t; i < cnt; i += 256) {
            uint p = pairbuf[lo + i];
            int pos = atomicAdd(&lcur[p >> 24], 1);
            lcsr[pos] = (int)(p & 0xFFFFFFu);
        }
        __syncthreads();
        for (int i = t; i < cnt; i += 256) csr[lo + i] = lcsr[i];
    } else {
        for (int i = t; i < cnt; i += 256) {
            uint p = pairbuf[lo + i];
            int pos = lo + atomicAdd(&lcur[p >> 24], 1);
            csr[pos] = (int)(p & 0xFFFFFFu);
        }
    }
}

// ---------------- fused agg + GEMM ----------------
// Agg: 16 groups x 16 lanes claim nodes via LDS counter; coalesced gather
// (16 lanes x uint4 = one 256B row per load, x4 unroll). EDGE_W=true: input g
// is UNSCALED -> per-edge dinv[s] weights (only layer 1 pays this).
// EDGE_W=false: input pre-scaled -> plain adds. Both write the GEMM output
// PRE-SCALED by dinv[row] (R12 convention downstream).

template <int NT, bool EDGE_W>
__device__ __forceinline__ void fused_agg_gemm(const ushort* __restrict__ g,
                                               const float* __restrict__ dinv,
                                               const int* __restrict__ rowptr,
                                               const int* __restrict__ csr,
                                               const float* __restrict__ bias,
                                               const ushort* __restrict__ Wt,
                                               ushort* __restrict__ C,
                                               int M, int ccols) {
    __shared__ ushort hs[32][136];
    __shared__ int nextNode;
    int t = threadIdx.x;
    if (t == 0) nextNode = 0;
    int l = t & 15;
    const uint4* g16 = (const uint4*)g;
    float4 bb0 = ((const float4*)bias)[2 * l];
    float4 bb1 = ((const float4*)bias)[2 * l + 1];
    __syncthreads();

    for (;;) {
        int idx = 0;
        if (l == 0) idx = atomicAdd(&nextNode, 1);
        idx = __shfl(idx, (t & 63) & ~15, 64);
        if (idx >= 32) break;
        int node = blockIdx.x * 32 + idx;
        int nd = min(node, M - 1);
        float dn = dinv[nd];
        float a[8];
        {
            uint4 p = g16[(size_t)nd * 16 + l];
            float u, v;
            if (EDGE_W) {
                unpack2(p.x, u, v); a[0] = u * dn; a[1] = v * dn;
                unpack2(p.y, u, v); a[2] = u * dn; a[3] = v * dn;
                unpack2(p.z, u, v); a[4] = u * dn; a[5] = v * dn;
                unpack2(p.w, u, v); a[6] = u * dn; a[7] = v * dn;
            } else {
                unpack2(p.x, a[0], a[1]); unpack2(p.y, a[2], a[3]);
                unpack2(p.z, a[4], a[5]); unpack2(p.w, a[6], a[7]);
            }
        }
        int e0 = rowptr[nd], e1 = rowptr[nd + 1];
        int e = e0;
        for (; e + 4 <= e1; e += 4) {
            int s0 = csr[e], s1 = csr[e + 1], s2 = csr[e + 2], s3 = csr[e + 3];
            float w0 = 1.f, w1 = 1.f, w2 = 1.f, w3 = 1.f;
            if (EDGE_W) { w0 = dinv[s0]; w1 = dinv[s1]; w2 = dinv[s2]; w3 = dinv[s3]; }
            uint4 p0 = g16[(size_t)s0 * 16 + l];
            uint4 p1 = g16[(size_t)s1 * 16 + l];
            uint4 p2 = g16[(size_t)s2 * 16 + l];
            uint4 p3 = g16[(size_t)s3 * 16 + l];
            float u, v;
            if (EDGE_W) {
                unpack2(p0.x, u, v); a[0] += u * w0; a[1] += v * w0;
                unpack2(p0.y, u, v); a[2] += u * w0; a[3] += v * w0;
                unpack2(p0.z, u, v); a[4] += u * w0; a[5] += v * w0;
                unpack2(p0.w, u, v); a[6] += u * w0; a[7] += v * w0;
                unpack2(p1.x, u, v); a[0] += u * w1; a[1] += v * w1;
                unpack2(p1.y, u, v); a[2] += u * w1; a[3] += v * w1;
                unpack2(p1.z, u, v); a[4] += u * w1; a[5] += v * w1;
                unpack2(p1.w, u, v); a[6] += u * w1; a[7] += v * w1;
                unpack2(p2.x, u, v); a[0] += u * w2; a[1] += v * w2;
                unpack2(p2.y, u, v); a[2] += u * w2; a[3] += v * w2;
                unpack2(p2.z, u, v); a[4] += u * w2; a[5] += v * w2;
                unpack2(p2.w, u, v); a[6] += u * w2; a[7] += v * w2;
                unpack2(p3.x, u, v); a[0] += u * w3; a[1] += v * w3;
                unpack2(p3.y, u, v); a[2] += u * w3; a[3] += v * w3;
                unpack2(p3.z, u, v); a[4] += u * w3; a[5] += v * w3;
                unpack2(p3.w, u, v); a[6] += u * w3; a[7] += v * w3;
            } else {
                unpack2(p0.x, u, v); a[0] += u; a[1] += v;
                unpack2(p0.y, u, v); a[2] += u; a[3] += v;
                unpack2(p0.z, u, v); a[4] += u; a[5] += v;
                unpack2(p0.w, u, v); a[6] += u; a[7] += v;
                unpack2(p1.x, u, v); a[0] += u; a[1] += v;
                unpack2(p1.y, u, v); a[2] += u; a[3] += v;
                unpack2(p1.z, u, v); a[4] += u; a[5] += v;
                unpack2(p1.w, u, v); a[6] += u; a[7] += v;
                unpack2(p2.x, u, v); a[0] += u; a[1] += v;
                unpack2(p2.y, u, v); a[2] += u; a[3] += v;
                unpack2(p2.z, u, v); a[4] += u; a[5] += v;
                unpack2(p2.w, u, v); a[6] += u; a[7] += v;
                unpack2(p3.x, u, v); a[0] += u; a[1] += v;
                unpack2(p3.y, u, v); a[2] += u; a[3] += v;
                unpack2(p3.z, u, v); a[4] += u; a[5] += v;
                unpack2(p3.w, u, v); a[6] += u; a[7] += v;
            }
        }
        for (; e < e1; e++) {
            int s = csr[e];
            float w = EDGE_W ? dinv[s] : 1.f;
            uint4 p = g16[(size_t)s * 16 + l];
            float u, v;
            unpack2(p.x, u, v); a[0] += u * w; a[1] += v * w;
            unpack2(p.y, u, v); a[2] += u * w; a[3] += v * w;
            unpack2(p.z, u, v); a[4] += u * w; a[5] += v * w;
            unpack2(p.w, u, v); a[6] += u * w; a[7] += v * w;
        }
        float o0 = fmaxf(a[0] * dn + bb0.x, 0.f);
        float o1 = fmaxf(a[1] * dn + bb0.y, 0.f);
        float o2 = fmaxf(a[2] * dn + bb0.z, 0.f);
        float o3 = fmaxf(a[3] * dn + bb0.w, 0.f);
        float o4 = fmaxf(a[4] * dn + bb1.x, 0.f);
        float o5 = fmaxf(a[5] * dn + bb1.y, 0.f);
        float o6 = fmaxf(a[6] * dn + bb1.z, 0.f);
        float o7 = fmaxf(a[7] * dn + bb1.w, 0.f);
        uint4 qv;
        qv.x = (uint)bf16rne(o0) | ((uint)bf16rne(o1) << 16);
        qv.y = (uint)bf16rne(o2) | ((uint)bf16rne(o3) << 16);
        qv.z = (uint)bf16rne(o4) | ((uint)bf16rne(o5) << 16);
        qv.w = (uint)bf16rne(o6) | ((uint)bf16rne(o7) << 16);
        *(uint4*)&hs[idx][l * 8] = qv;
    }
    __syncthreads();

    // GEMM from LDS: 4 waves = 2 row-halves x 2 n-tile-halves; PRE-SCALED out.
    int wave = t >> 6, lane = t & 63;
    int m16 = lane & 15, quad = lane >> 4;
    int rowHalf = wave & 1;
    int ntHalf = wave >> 1;
    constexpr int NTH = (NT + 1) / 2;
    int ntStart = ntHalf * NTH;
    int ntEnd = ntHalf ? NT : NTH;

    f32x4 acc[NTH];
#pragma unroll
    for (int i = 0; i < NTH; i++) acc[i] = (f32x4){0.f, 0.f, 0.f, 0.f};
#pragma unroll
    for (int it = 0; it < 4; it++) {
        bf16x8 af = *(const bf16x8*)&hs[rowHalf * 16 + m16][it * 32 + quad * 8];
        for (int nt = ntStart; nt < ntEnd; nt++) {
            bf16x8 bfr = *(const bf16x8*)(Wt + (size_t)(nt * 16 + m16) * 128 + it * 32 + quad * 8);
            acc[nt - ntStart] = __builtin_amdgcn_mfma_f32_16x16x32_bf16(af, bfr, acc[nt - ntStart], 0, 0, 0);
        }
    }
    int rowBase = blockIdx.x * 32 + rowHalf * 16 + quad * 4;
    float dnv[4];
#pragma unroll
    for (int r = 0; r < 4; r++) dnv[r] = dinv[min(rowBase + r, M - 1)];
    for (int nt = ntStart; nt < ntEnd; nt++) {
        int col = nt * 16 + m16;
        if (col >= ccols) continue;
#pragma unroll
        for (int r = 0; r < 4; r++) {
            int row = rowBase + r;
            if (row < M) C[(size_t)row * ccols + col] = bf16rne(acc[nt - ntStart][r] * dnv[r]);
        }
    }
}

__global__ __launch_bounds__(256) void k_fusedA(const ushort* __restrict__ g,
                                                const float* __restrict__ dinv,
                                                const int* __restrict__ rowptr,
                                                const int* __restrict__ csr,
                                                const float* __restrict__ bias,
                                                const ushort* __restrict__ Wt,
                                                ushort* __restrict__ C, int M) {
    fused_agg_gemm<8, true>(g, dinv, rowptr, csr, bias, Wt, C, M, 128);  // unscaled in
}

__global__ __launch_bounds__(256) void k_fusedB(const ushort* __restrict__ g,
                                                const float* __restrict__ dinv,
                                                const int* __restrict__ rowptr,
                                                const int* __restrict__ csr,
                                                const float* __restrict__ bias,
                                                const ushort* __restrict__ Wt,
                                                ushort* __restrict__ C, int M) {
    fused_agg_gemm<3, false>(g, dinv, rowptr, csr, bias, Wt, C, M, 40);  // pre-scaled in
}

// ---------------- final aggregation over 40-col rows (pre-scaled g3) ----------------

__global__ __launch_bounds__(256) void k_agg40_b(const ushort* __restrict__ g3,
                                                 const float* __restrict__ dinv,
                                                 const int* __restrict__ rowptr,
                                                 const int* __restrict__ csr,
                                                 const float* __restrict__ bias,
                                                 float* __restrict__ out, int N) {
    int t = threadIdx.x;
    if (t >= 250) return;
    int grp = t / 10;
    int l = t - grp * 10;
    int node = blockIdx.x * 25 + grp;
    if (node >= N) return;
    const uint2* gp = (const uint2*)g3;
    float dn = dinv[node];
    float a0, a1, a2, a3;
    {
        uint2 p = gp[(size_t)node * 10 + l];
        unpack2(p.x, a0, a1);
        unpack2(p.y, a2, a3);
    }
    int e0 = rowptr[node], e1 = rowptr[node + 1];
    int e = e0;
    for (; e + 4 <= e1; e += 4) {
        int s0 = csr[e], s1 = csr[e + 1], s2 = csr[e + 2], s3 = csr[e + 3];
        uint2 p0 = gp[(size_t)s0 * 10 + l];
        uint2 p1 = gp[(size_t)s1 * 10 + l];
        uint2 p2 = gp[(size_t)s2 * 10 + l];
        uint2 p3 = gp[(size_t)s3 * 10 + l];
        float u, v;
        unpack2(p0.x, u, v); a0 += u; a1 += v;
        unpack2(p0.y, u, v); a2 += u; a3 += v;
        unpack2(p1.x, u, v); a0 += u; a1 += v;
        unpack2(p1.y, u, v); a2 += u; a3 += v;
        unpack2(p2.x, u, v); a0 += u; a1 += v;
        unpack2(p2.y, u, v); a2 += u; a3 += v;
        unpack2(p3.x, u, v); a0 += u; a1 += v;
        unpack2(p3.y, u, v); a2 += u; a3 += v;
    }
    for (; e < e1; e++) {
        int s = csr[e];
        uint2 p = gp[(size_t)s * 10 + l];
        float u, v;
        unpack2(p.x, u, v); a0 += u; a1 += v;
        unpack2(p.y, u, v); a2 += u; a3 += v;
    }
    float4 bb = ((const float4*)bias)[l];
    float4 o;
    o.x = a0 * dn + bb.x;
    o.y = a1 * dn + bb.y;
    o.z = a2 * dn + bb.z;
    o.w = a3 * dn + bb.w;
    ((float4*)out)[(size_t)node * 10 + l] = o;
}

// ---------------- launch ----------------

extern "C" void kernel_launch(void* const* d_in, const int* in_sizes, int n_in,
                              void* d_out, int out_size, void* d_ws, size_t ws_size,
                              hipStream_t stream) {
    const float* x  = (const float*)d_in[0];
    const int* eidx = (const int*)d_in[1];
    const float* W1 = (const float*)d_in[2];
    const float* b1 = (const float*)d_in[3];
    const float* Wm = (const float*)d_in[4];
    const float* bm = (const float*)d_in[5];
    const float* W2 = (const float*)d_in[6];
    const float* b2 = (const float*)d_in[7];
    float* out = (float*)d_out;

    int N = in_sizes[0] / 128;
    int E = in_sizes[1] / 2;
    const int* src = eidx;
    const int* dst = eidx + E;
    int nbuck = (N + 255) >> 8;
    int ntile = (E + 4095) / 4096;

    char* ws = (char*)d_ws;
    size_t off = 0;
    auto alloc = [&](size_t bytes) -> void* {
        void* p = ws + off;
        off += (bytes + 255) & ~(size_t)255;
        return p;
    };
    float*  dinv    = (float*)alloc((size_t)N * 4);
    int*    rowptr  = (int*)alloc(((size_t)N + 1) * 4);
    int*    csr     = (int*)alloc((size_t)E * 4);
    uint*   pairbuf = (uint*)alloc((size_t)E * 4);
    int*    bcnt    = (int*)alloc(512 * 4);
    int*    bbase   = (int*)alloc(513 * 4);
    int*    bcur    = (int*)alloc(512 * 4);
    ushort* w1t     = (ushort*)alloc(128 * 128 * 2);
    ushort* wmt     = (ushort*)alloc(128 * 128 * 2);
    ushort* w2t     = (ushort*)alloc(48 * 128 * 2);
    ushort* gbuf    = (ushort*)alloc((size_t)N * 128 * 2);  // layer-1 out, UNSCALED
    ushort* gbuf2   = (ushort*)alloc((size_t)N * 128 * 2);  // layer-2 out, pre-scaled
    ushort* g3      = (ushort*)alloc((size_t)N * 40 * 2);   // layer-3 out, pre-scaled

    int gblk64 = (N + 63) / 64;
    int gblk32 = (N + 31) / 32;

    hipMemsetAsync(bcnt, 0, 512 * 4, stream);
    // castT (152 blocks) || bhist (ntile blocks)
    k_pre1<<<152 + ntile, 256, 0, stream>>>(W1, Wm, W2, w1t, wmt, w2t, dst, bcnt, E);
    k_bscan<<<1, 512, 0, stream>>>(bcnt, bbase, bcur, nbuck);
    // binpack (ntile blocks) || gemm1 (gblk64 blocks, unscaled output)
    k_pack_gemm<<<ntile + gblk64, 256, 0, stream>>>(src, dst, bcur, pairbuf, E, nbuck,
                                                    ntile, x, w1t, gbuf, N);
    k_csrbuild<<<nbuck, 256, 0, stream>>>(pairbuf, bbase, rowptr, dinv, csr, N, nbuck);
    // layer-1 agg (per-edge dinv on unscaled gbuf) + layer-2 GEMM (pre-scaled out)
    k_fusedA<<<gblk32, 256, 0, stream>>>(gbuf, dinv, rowptr, csr, b1, wmt, gbuf2, N);
    // layer-2 agg (pre-scaled, plain adds) + layer-3 GEMM (pre-scaled out)
    k_fusedB<<<gblk32, 256, 0, stream>>>(gbuf2, dinv, rowptr, csr, bm, w2t, g3, N);
    // final aggregation
    k_agg40_b<<<(N + 24) / 25, 256, 0, stream>>>(g3, dinv, rowptr, csr, b2, out, N);
}